// Round 3
// baseline (239.861 us; speedup 1.0000x reference)
//
#include <hip/hip_runtime.h>
#include <math.h>

// Sparse EdgeConvE, latency-optimized:
//  - scan_kernel builds per-row compact edge lists ONCE (shared by both convs)
//  - edgeconv blocks = (node, 8-edge chunk): one gather latency per block,
//    2 barriers total, partial sums combined via atomicAdd (fp32 order noise
//    ~1e-6 << 1.9e-2 threshold)
//  - x_i contribution hoisted: feat = [x_j | e], c_xi per-node bias via shfl

#define NN 768
#define FF 64
#define DE 32
#define HH 64
#define EB 8
#define PD 100          // padded feat stride (96 used) - kills 4-way LDS write conflict
#define CAP 128         // per-row edge-list capacity (mean 38.4, sd 6 -> 14 sigma)
#define MAXB (CAP / EB) // 16 chunk-blocks per node

__global__ __launch_bounds__(256) void scan_kernel(
    const float* __restrict__ A, int* __restrict__ cnt,
    int* __restrict__ jl, float* __restrict__ al)
{
  const int i = blockIdx.x;
  const int tid = threadIdx.x;
  __shared__ int s_cnt;
  if (tid == 0) s_cnt = 0;
  __syncthreads();
  for (int j = tid; j < NN; j += 256) {
    float a = A[i * NN + j];
    if (a != 0.0f) {
      int p = atomicAdd(&s_cnt, 1);
      if (p < CAP) { jl[i * CAP + p] = j; al[i * CAP + p] = a; }
    }
  }
  __syncthreads();
  if (tid == 0) cnt[i] = min(s_cnt, CAP);
}

__global__ __launch_bounds__(256) void edgeconv_kernel(
    const int* __restrict__ cnt, const int* __restrict__ jl,
    const float* __restrict__ al, const float* __restrict__ x,
    const float* __restrict__ e, const float* __restrict__ Wa,
    const float* __restrict__ ba, const float* __restrict__ Wb,
    const float* __restrict__ bb, float* __restrict__ xout)
{
  const int i = blockIdx.x >> 4;            // node
  const int chunk = blockIdx.x & (MAXB - 1);
  const int c = cnt[i];
  const int t0 = chunk * EB;
  if (t0 >= c) return;

  const int tid = threadIdx.x;
  const int lane = tid & 63;
  const int wv = tid >> 6;
  const int slice = lane >> 4;              // 0..3
  const int k = wv * 16 + (lane & 15);      // output channel 0..63

  __shared__ __align__(16) float s_feat[EB * PD];  // [xj(64) | e(32)] per edge
  __shared__ __align__(16) float s_h1[EB * HH];

  // ---- stage this chunk's 8 edges: 128 threads load xj, 64 load e ----
  if (tid < 192) {
    const bool is_xj = tid < 128;
    const int rb = is_xj ? (tid >> 4) : ((tid - 128) >> 3);
    const int ru = is_xj ? (tid & 15) : ((tid - 128) & 7);
    const int idx = t0 + rb < c ? t0 + rb : c - 1;
    const int j = jl[i * CAP + idx];
    float4 r;
    if (is_xj) r = ((const float4*)(x + (size_t)j * FF))[ru];
    else       r = ((const float4*)(e + ((size_t)i * NN + j) * DE))[ru];
    *(float4*)(s_feat + rb * PD + (is_xj ? ru * 4 : FF + ru * 4)) = r;
  }

  // ---- per-lane register weights (hot 40KB table, L2) ----
  float w1[24];
#pragma unroll
  for (int t = 0; t < 24; ++t) w1[t] = Wa[(size_t)(64 + slice * 24 + t) * HH + k];
  float w2[16];
#pragma unroll
  for (int t = 0; t < 16; ++t) w2[t] = Wb[(size_t)(slice * 16 + t) * HH + k];
  const float bias2 = bb[k];

  // ---- per-node bias c_xi[k] = sum_d xi[d]*(Wa[d][k]-Wa[64+d][k]) + ba[k]
  // reduced via shfl, broadcast via shfl (no LDS, no barrier)
  float cxi;
  {
    float p = 0.0f;
#pragma unroll
    for (int t = 0; t < 16; ++t) {
      int d = slice * 16 + t;
      p = fmaf(x[i * FF + d], Wa[(size_t)d * HH + k] - Wa[(size_t)(64 + d) * HH + k], p);
    }
    p += __shfl_down(p, 32);
    p += __shfl_down(p, 16);
    cxi = __shfl(p, lane & 15) + ba[k];
  }

  // ---- edge weights for accumulation ----
  float ea[EB];
#pragma unroll
  for (int b = 0; b < EB; ++b)
    ea[b] = (t0 + b < c) ? al[i * CAP + t0 + b] : 0.0f;

  __syncthreads();  // staging visible

  // ---- layer 1: all 8 edges ----
#pragma unroll
  for (int b = 0; b < EB; ++b) {
    const float4* f4 = (const float4*)(s_feat + b * PD + slice * 24);
    float p = 0.0f;
#pragma unroll
    for (int u = 0; u < 6; ++u) {
      float4 f = f4[u];
      p = fmaf(f.x, w1[4 * u + 0], p);
      p = fmaf(f.y, w1[4 * u + 1], p);
      p = fmaf(f.z, w1[4 * u + 2], p);
      p = fmaf(f.w, w1[4 * u + 3], p);
    }
    p += __shfl_down(p, 32);
    p += __shfl_down(p, 16);
    if (lane < 16) s_h1[b * HH + k] = fmaxf(p + cxi, 0.0f);
  }
  __syncthreads();  // h1 visible

  // ---- layer 2: all 8 edges, accumulate weighted relu ----
  float acc = 0.0f;
#pragma unroll
  for (int b = 0; b < EB; ++b) {
    const float4* h4 = (const float4*)(s_h1 + b * HH + slice * 16);
    float q = 0.0f;
#pragma unroll
    for (int u = 0; u < 4; ++u) {
      float4 h = h4[u];
      q = fmaf(h.x, w2[4 * u + 0], q);
      q = fmaf(h.y, w2[4 * u + 1], q);
      q = fmaf(h.z, w2[4 * u + 2], q);
      q = fmaf(h.w, w2[4 * u + 3], q);
    }
    q += __shfl_down(q, 32);
    q += __shfl_down(q, 16);
    if (lane < 16) acc = fmaf(ea[b], fmaxf(q + bias2, 0.0f), acc);
  }

  if (lane < 16) atomicAdd(&xout[i * HH + k], acc);
}

// x2[768,64] -> relu(x2 @ W3[64,128] + b3) -> sigmoid(@ W4[128,1] + b4)
__global__ __launch_bounds__(128) void final_kernel(
    const float* __restrict__ x2, const float* __restrict__ W3,
    const float* __restrict__ b3, const float* __restrict__ W4,
    const float* __restrict__ b4, float* __restrict__ out)
{
  const int i = blockIdx.x;
  const int t = threadIdx.x;  // 0..127
  const int lane = t & 63;
  const int wv = t >> 6;
  __shared__ float sx[64];
  __shared__ float s_red[2];
  if (t < 64) sx[t] = x2[i * 64 + t];
  __syncthreads();
  float p = b3[t];
#pragma unroll
  for (int c = 0; c < 64; ++c) p = fmaf(sx[c], W3[c * 128 + t], p);
  p = fmaxf(p, 0.0f);
  float v = p * W4[t];
  v += __shfl_down(v, 32);
  v += __shfl_down(v, 16);
  v += __shfl_down(v, 8);
  v += __shfl_down(v, 4);
  v += __shfl_down(v, 2);
  v += __shfl_down(v, 1);
  if (lane == 0) s_red[wv] = v;
  __syncthreads();
  if (t == 0) {
    float z = s_red[0] + s_red[1] + b4[0];
    out[i] = 1.0f / (1.0f + expf(-z));
  }
}

extern "C" void kernel_launch(void* const* d_in, const int* in_sizes, int n_in,
                              void* d_out, int out_size, void* d_ws, size_t ws_size,
                              hipStream_t stream) {
  const float* A   = (const float*)d_in[0];
  const float* x   = (const float*)d_in[1];
  const float* e   = (const float*)d_in[2];
  const float* W1a = (const float*)d_in[3];
  const float* b1a = (const float*)d_in[4];
  const float* W1b = (const float*)d_in[5];
  const float* b1b = (const float*)d_in[6];
  const float* W2a = (const float*)d_in[7];
  const float* b2a = (const float*)d_in[8];
  const float* W2b = (const float*)d_in[9];
  const float* b2b = (const float*)d_in[10];
  const float* W3  = (const float*)d_in[11];
  const float* b3  = (const float*)d_in[12];
  const float* W4  = (const float*)d_in[13];
  const float* b4  = (const float*)d_in[14];
  float* out = (float*)d_out;

  // ws layout (floats)
  float* x1 = (float*)d_ws;                 // [768*64]
  float* x2 = x1 + NN * HH;                 // [768*64]
  int*   cnt = (int*)(x2 + NN * HH);        // [768]
  int*   jl  = cnt + NN;                    // [768*CAP]
  float* al  = (float*)(jl + NN * CAP);     // [768*CAP]

  hipMemsetAsync(x1, 0, 2 * NN * HH * sizeof(float), stream);

  scan_kernel<<<NN, 256, 0, stream>>>(A, cnt, jl, al);
  edgeconv_kernel<<<NN * MAXB, 256, 0, stream>>>(cnt, jl, al, x,  e, W1a, b1a, W1b, b1b, x1);
  edgeconv_kernel<<<NN * MAXB, 256, 0, stream>>>(cnt, jl, al, x1, e, W2a, b2a, W2b, b2b, x2);
  final_kernel<<<NN, 128, 0, stream>>>(x2, W3, b3, W4, b4, out);
}

// Round 4
// 206.032 us; speedup vs baseline: 1.1642x; 1.1642x over previous
//
#include <hip/hip_runtime.h>
#include <math.h>

// Sparse EdgeConvE, wave-per-edge formulation (no barriers in hot path).
// A is binary -> aggregation weight is 1.0; layer 1 is linear in [x_i,x_j,e]:
//   h1 = relu( U[i] + V[j] + e_ij @ We ),  U = x@(Wxi-Wxj)+ba, V = x@Wxj
//   h2 = relu( h1 @ Wb + bb );  out[i] += h2   (atomicAdd)
// Lane k owns output channel k; We/Wb columns live in registers; h1 is
// broadcast through a per-wave LDS line (wave-synchronous).

#define NN 768
#define FF 64
#define DE 32
#define HH 64
#define CPW 8                 // edges per wave
#define ECAP (NN * 128)       // flat edge-list capacity

__global__ __launch_bounds__(256) void scan_kernel(
    const float* __restrict__ A, int* __restrict__ gcnt, int* __restrict__ edges)
{
  const int i = blockIdx.x;
  const int tid = threadIdx.x;
  __shared__ int s_cnt, s_base;
  __shared__ int s_j[NN];
  if (tid == 0) s_cnt = 0;
  __syncthreads();
  for (int j = tid; j < NN; j += 256) {
    if (A[i * NN + j] != 0.0f) {
      int p = atomicAdd(&s_cnt, 1);
      s_j[p] = j;
    }
  }
  __syncthreads();
  if (tid == 0) s_base = atomicAdd(gcnt, s_cnt);
  __syncthreads();
  const int c = s_cnt, b = s_base;
  for (int t = tid; t < c; t += 256) edges[b + t] = (i << 10) | s_j[t];
}

// U[r][c] = sum_d x[r][d]*(W[d][c]-W[64+d][c]) + bias[c];  V[r][c] = sum_d x[r][d]*W[64+d][c]
__global__ __launch_bounds__(256, 4) void uv_kernel(
    const float* __restrict__ x, const float* __restrict__ W,
    const float* __restrict__ bias, float* __restrict__ U, float* __restrict__ V)
{
  const int tid = threadIdx.x;
  const int rr = tid >> 6, c = tid & 63;
  const int r = blockIdx.x * 4 + rr;
  __shared__ float sx[4][64];
  sx[rr][c] = x[r * 64 + c];
  __syncthreads();
  float u = bias[c], v = 0.0f;
#pragma unroll
  for (int d = 0; d < 64; ++d) {
    float xv = sx[rr][d];
    float wxi = W[d * 64 + c];
    float wxj = W[(64 + d) * 64 + c];
    u = fmaf(xv, wxi - wxj, u);
    v = fmaf(xv, wxj, v);
  }
  U[r * 64 + c] = u;
  V[r * 64 + c] = v;
}

__global__ __launch_bounds__(256, 4) void edge_kernel(
    const int* __restrict__ gcnt, const int* __restrict__ edges,
    const float* __restrict__ U, const float* __restrict__ V,
    const float* __restrict__ e, const float* __restrict__ We,
    const float* __restrict__ Wb, const float* __restrict__ bb,
    float* __restrict__ xout)
{
  const int tid = threadIdx.x, lane = tid & 63, wv = tid >> 6;
  const int M = gcnt[0];
  const int base = (blockIdx.x * 4 + wv) * CPW;
  if (base >= M) return;

  __shared__ __align__(16) float sh1[4][64];

  // per-lane weight columns (k = lane)
  float w1e[32];
#pragma unroll
  for (int t = 0; t < 32; ++t) w1e[t] = We[t * HH + lane];
  float w2[64];
#pragma unroll
  for (int c = 0; c < 64; ++c) w2[c] = Wb[c * HH + lane];
  const float bbr = bb[lane];

  const int mend = base + CPW < M ? base + CPW : M;
  for (int m = base; m < mend; ++m) {
    const int p = edges[m];
    const int i = p >> 10, j = p & 1023;

    float4 h4;
    h4.x = U[(i << 6) + lane] + V[(j << 6) + lane];
    h4.y = 0.0f; h4.z = 0.0f; h4.w = 0.0f;
    const float4* ep = (const float4*)(e + (size_t)(i * NN + j) * DE);
#pragma unroll
    for (int u = 0; u < 8; ++u) {
      float4 f = ep[u];   // uniform address: 1 txn, broadcast to lanes
      h4.x = fmaf(f.x, w1e[4 * u + 0], h4.x);
      h4.y = fmaf(f.y, w1e[4 * u + 1], h4.y);
      h4.z = fmaf(f.z, w1e[4 * u + 2], h4.z);
      h4.w = fmaf(f.w, w1e[4 * u + 3], h4.w);
    }
    const float h1 = fmaxf((h4.x + h4.y) + (h4.z + h4.w), 0.0f);

    __builtin_amdgcn_wave_barrier();
    sh1[wv][lane] = h1;                 // wave-synchronous LDS broadcast line
    __builtin_amdgcn_wave_barrier();

    float4 q4;
    q4.x = bbr; q4.y = 0.0f; q4.z = 0.0f; q4.w = 0.0f;
    const float4* hp = (const float4*)sh1[wv];
#pragma unroll
    for (int u = 0; u < 16; ++u) {
      float4 g = hp[u];   // uniform LDS address: broadcast, conflict-free
      q4.x = fmaf(g.x, w2[4 * u + 0], q4.x);
      q4.y = fmaf(g.y, w2[4 * u + 1], q4.y);
      q4.z = fmaf(g.z, w2[4 * u + 2], q4.z);
      q4.w = fmaf(g.w, w2[4 * u + 3], q4.w);
    }
    const float h2 = fmaxf((q4.x + q4.y) + (q4.z + q4.w), 0.0f);
    atomicAdd(&xout[(i << 6) + lane], h2);
    __builtin_amdgcn_wave_barrier();    // keep next iter's sh1 write below these reads
  }
}

// x2[768,64] -> relu(x2 @ W3[64,128] + b3) -> sigmoid(@ W4[128,1] + b4)
__global__ __launch_bounds__(128) void final_kernel(
    const float* __restrict__ x2, const float* __restrict__ W3,
    const float* __restrict__ b3, const float* __restrict__ W4,
    const float* __restrict__ b4, float* __restrict__ out)
{
  const int i = blockIdx.x;
  const int t = threadIdx.x;
  const int lane = t & 63;
  const int wv = t >> 6;
  __shared__ float sx[64];
  __shared__ float s_red[2];
  if (t < 64) sx[t] = x2[i * 64 + t];
  __syncthreads();
  float p = b3[t];
#pragma unroll
  for (int c = 0; c < 64; ++c) p = fmaf(sx[c], W3[c * 128 + t], p);
  p = fmaxf(p, 0.0f);
  float v = p * W4[t];
  v += __shfl_down(v, 32);
  v += __shfl_down(v, 16);
  v += __shfl_down(v, 8);
  v += __shfl_down(v, 4);
  v += __shfl_down(v, 2);
  v += __shfl_down(v, 1);
  if (lane == 0) s_red[wv] = v;
  __syncthreads();
  if (t == 0) {
    float z = s_red[0] + s_red[1] + b4[0];
    out[i] = 1.0f / (1.0f + expf(-z));
  }
}

extern "C" void kernel_launch(void* const* d_in, const int* in_sizes, int n_in,
                              void* d_out, int out_size, void* d_ws, size_t ws_size,
                              hipStream_t stream) {
  const float* A   = (const float*)d_in[0];
  const float* x   = (const float*)d_in[1];
  const float* e   = (const float*)d_in[2];
  const float* W1a = (const float*)d_in[3];
  const float* b1a = (const float*)d_in[4];
  const float* W1b = (const float*)d_in[5];
  const float* b1b = (const float*)d_in[6];
  const float* W2a = (const float*)d_in[7];
  const float* b2a = (const float*)d_in[8];
  const float* W2b = (const float*)d_in[9];
  const float* b2b = (const float*)d_in[10];
  const float* W3  = (const float*)d_in[11];
  const float* b3  = (const float*)d_in[12];
  const float* W4  = (const float*)d_in[13];
  const float* b4  = (const float*)d_in[14];
  float* out = (float*)d_out;

  // ws layout: [gcnt(16 ints) | x1 | x2 | U1 | V1 | U2 | V2 | edges]
  int*   gcnt  = (int*)d_ws;
  float* x1    = (float*)d_ws + 16;
  float* x2    = x1 + NN * HH;
  float* U1    = x2 + NN * HH;
  float* V1    = U1 + NN * HH;
  float* U2    = V1 + NN * HH;
  float* V2    = U2 + NN * HH;
  int*   edges = (int*)(V2 + NN * HH);

  // zero gcnt + x1 + x2 in one shot
  hipMemsetAsync(d_ws, 0, (16 + 2 * NN * HH) * sizeof(float), stream);

  scan_kernel<<<NN, 256, 0, stream>>>(A, gcnt, edges);
  uv_kernel<<<NN / 4, 256, 0, stream>>>(x, W1a, b1a, U1, V1);
  edge_kernel<<<1536, 256, 0, stream>>>(gcnt, edges, U1, V1, e, W1a + 128 * HH,
                                        W1b, b1b, x1);
  uv_kernel<<<NN / 4, 256, 0, stream>>>(x1, W2a, b2a, U2, V2);
  edge_kernel<<<1536, 256, 0, stream>>>(gcnt, edges, U2, V2, e, W2a + 128 * HH,
                                        W2b, b2b, x2);
  final_kernel<<<NN, 128, 0, stream>>>(x2, W3, b3, W4, b4, out);
}